// Round 2
// baseline (447.635 us; speedup 1.0000x reference)
//
#include <hip/hip_runtime.h>
#include <hip/hip_bf16.h>
#include <stdint.h>

#define NN 32768
#define HH 256

typedef short bf16x8 __attribute__((ext_vector_type(8)));
typedef float f32x4 __attribute__((ext_vector_type(4)));
typedef unsigned short ushort_t;
typedef unsigned short ushort8_t __attribute__((ext_vector_type(8)));
typedef unsigned short ushort4_t __attribute__((ext_vector_type(4)));

__device__ __forceinline__ ushort_t f2bf(float f) {
  union { float f; unsigned u; } v; v.f = f;
  unsigned u = v.u;
  unsigned r = (u + 0x7FFFu + ((u >> 16) & 1u)) >> 16;  // RNE (cold paths)
  return (ushort_t)r;
}
__device__ __forceinline__ float bf2f(ushort_t h) {
  union { unsigned u; float f; } v; v.u = ((unsigned)h) << 16;
  return v.f;
}
__device__ __forceinline__ float asf(unsigned u) {
  union { unsigned u; float f; } v; v.u = u; return v.f;
}
// HW packed f32->bf16 (RNE), 1 instr per 2 elems
__device__ __forceinline__ unsigned cvt_pk(float lo, float hi) {
  unsigned r;
  asm("v_cvt_pk_bf16_f32 %0, %1, %2" : "=v"(r) : "v"(lo), "v"(hi));
  return r;
}
__device__ __forceinline__ float sigmoidf_(float x) {
  float e = __builtin_amdgcn_exp2f(-1.4426950408889634f * x);
  return __builtin_amdgcn_rcpf(1.f + e);
}
__device__ __forceinline__ float tanhf_(float x) {
  float ax = fminf(fabsf(x), 15.f);
  float e = __builtin_amdgcn_exp2f(2.8853900817779268f * ax);  // exp(2ax)
  float t = (e - 1.f) * __builtin_amdgcn_rcpf(e + 1.f);
  return copysignf(t, x);
}
// XOR swizzle: 16B chunks within a 256-elem (512B) row, spread across rows&7
__device__ __forceinline__ int swz(int row, int col) {
  return row * 256 + ((((col >> 3) ^ (row & 7)) << 3) | (col & 7));
}

// ---------------- prep: weights -> bf16, transposed to [N][K] ----------------
__global__ void k_prep(const float* __restrict__ W_iou, const float* __restrict__ W_fin,
                       const float* __restrict__ W_f, const float* __restrict__ W_aggr,
                       ushort_t* __restrict__ WcatT, ushort_t* __restrict__ WfT,
                       ushort_t* __restrict__ WaggrT) {
  int tid = blockIdx.x * 256 + threadIdx.x;
  if (tid < 262144) {                       // WcatT [1024][256]
    int n = tid >> 8, k = tid & 255;
    float v = (n < 768) ? W_iou[k * 768 + n] : W_fin[k * 256 + (n - 768)];
    WcatT[tid] = f2bf(v);
  } else if (tid < 327680) {                // WfT [256][256]
    int t2 = tid - 262144; int n = t2 >> 8, k = t2 & 255;
    WfT[t2] = f2bf(W_f[k * 256 + n]);
  } else if (tid < 524288) {                // WaggrT [768][256]
    int t3 = tid - 327680; int n = t3 >> 8, k = t3 & 255;
    WaggrT[t3] = f2bf(W_aggr[k * 768 + n]);
  }
}

// ---------------- k1: iouf = x @ [W_iou | W_fin] + bias ----------------------
// 64 rows x 256 cols per block; A staged once, 4 B-subtiles of 64 cols.
__global__ __launch_bounds__(256) void k_iou(
    const float* __restrict__ x, const ushort_t* __restrict__ WcatT,
    const float* __restrict__ b_iou, const float* __restrict__ b_fin,
    ushort_t* __restrict__ io_out, ushort_t* __restrict__ cau_out,
    ushort_t* __restrict__ f_out) {
  __shared__ __align__(16) ushort_t As[64 * 256];
  __shared__ __align__(16) ushort_t Bs[64 * 256];
  __shared__ float bias_s[64];
  const int tid = threadIdx.x;
  const int mt = blockIdx.x >> 2;
  const int nt = blockIdx.x & 3;

  const float4* Ag = (const float4*)(x + (size_t)mt * 64 * 256);
#pragma unroll
  for (int it = 0; it < 16; ++it) {
    int idx4 = tid + it * 256;
    float4 v = Ag[idx4];
    int row = idx4 >> 6, col = (idx4 & 63) << 2;
    uint2 b = { cvt_pk(v.x, v.y), cvt_pk(v.z, v.w) };
    *(uint2*)&As[swz(row, col)] = b;
  }

  const int lane = tid & 63, wv = tid >> 6;
  const int g = lane >> 4, r = lane & 15;
  const int wm = wv >> 1, wn = wv & 1;

  for (int s = 0; s < 4; ++s) {
    __syncthreads();
    const int ct = nt * 4 + s;  // 64-col tile index in [0,16)
    const ushort8_t* Bg = (const ushort8_t*)(WcatT + (size_t)ct * 64 * 256);
#pragma unroll
    for (int it = 0; it < 8; ++it) {
      int idx8 = tid + it * 256;
      int row = idx8 >> 5, col = (idx8 & 31) << 3;
      *(ushort8_t*)&Bs[swz(row, col)] = Bg[idx8];
    }
    if (tid < 64) {
      int c = ct * 64 + tid;
      bias_s[tid] = (c < 768) ? b_iou[c] : b_fin[c - 768];
    }
    __syncthreads();

    f32x4 acc[2][2] = {};
#pragma unroll
    for (int kb = 0; kb < 8; ++kb) {
      int kc = kb * 32 + g * 8;
      bf16x8 a0 = *(const bf16x8*)&As[swz(wm * 32 + r, kc)];
      bf16x8 a1 = *(const bf16x8*)&As[swz(wm * 32 + 16 + r, kc)];
      bf16x8 b0 = *(const bf16x8*)&Bs[swz(wn * 32 + r, kc)];
      bf16x8 b1 = *(const bf16x8*)&Bs[swz(wn * 32 + 16 + r, kc)];
      acc[0][0] = __builtin_amdgcn_mfma_f32_16x16x32_bf16(a0, b0, acc[0][0], 0, 0, 0);
      acc[0][1] = __builtin_amdgcn_mfma_f32_16x16x32_bf16(a0, b1, acc[0][1], 0, 0, 0);
      acc[1][0] = __builtin_amdgcn_mfma_f32_16x16x32_bf16(a1, b0, acc[1][0], 0, 0, 0);
      acc[1][1] = __builtin_amdgcn_mfma_f32_16x16x32_bf16(a1, b1, acc[1][1], 0, 0, 0);
    }
#pragma unroll
    for (int mi = 0; mi < 2; ++mi)
#pragma unroll
      for (int ni = 0; ni < 2; ++ni)
#pragma unroll
        for (int i = 0; i < 4; ++i) {
          int node = mt * 64 + wm * 32 + mi * 16 + g * 4 + i;
          int colL = wn * 32 + ni * 16 + r;
          int col = ct * 64 + colL;
          ushort_t hv = f2bf(acc[mi][ni][i] + bias_s[colL]);
          if (col < 512)      io_out[node * 512 + col] = hv;
          else if (col < 768) cau_out[node * 512 + (col - 256)] = hv;
          else                f_out[node * 256 + (col - 768)] = hv;
        }
  }
}

// ---------------- k2: f-path, transposed MFMA (8 nodes / 64 rows per block) --
// A-operand = W_f^T fragments (global, L2-hot); B-operand = nh rows (LDS).
// Lane (g,r) of the C-tile holds row (rowbase+r), cols (cbase+g*4 .. +3)
// -> nc is one coalesced float4; child-reduce = 3x shfl_xor.
__global__ __launch_bounds__(256, 4) void k_fgate(
    const float* __restrict__ nh, const float* __restrict__ nc,
    const ushort_t* __restrict__ WfT, const float* __restrict__ b_f,
    const ushort_t* __restrict__ f_in,
    ushort_t* __restrict__ cau_out, ushort_t* __restrict__ hsum_out) {
  __shared__ __align__(16) ushort_t As[64 * 256];   // nh tile, bf16 swizzled
  __shared__ __align__(16) ushort_t fin_s[8 * 256]; // f_input, bf16
  __shared__ float bias_s[256];
  const int tid = threadIdx.x;
  const int blk = blockIdx.x;

  // stage nh (64 rows) -> bf16 LDS
  const float4* Ag = (const float4*)(nh + (size_t)blk * 64 * 256);
#pragma unroll
  for (int it = 0; it < 16; ++it) {
    int idx4 = tid + it * 256;
    float4 v = Ag[idx4];
    int row = idx4 >> 6, col = (idx4 & 63) << 2;
    uint2 b = { cvt_pk(v.x, v.y), cvt_pk(v.z, v.w) };
    *(uint2*)&As[swz(row, col)] = b;
  }
  ((ushort8_t*)fin_s)[tid] = ((const ushort8_t*)(f_in + blk * 2048))[tid];
  bias_s[tid] = b_f[tid];
  __syncthreads();

  // hsum: one (node, 8-col chunk) per thread, vector LDS reads
  {
    int node = tid >> 5, chunk = tid & 31;
    float s[8] = {};
#pragma unroll
    for (int c = 0; c < 8; ++c) {
      uint4 v = *(const uint4*)&As[swz(node * 8 + c, chunk * 8)];
      s[0] += asf(v.x << 16); s[1] += asf(v.x & 0xffff0000u);
      s[2] += asf(v.y << 16); s[3] += asf(v.y & 0xffff0000u);
      s[4] += asf(v.z << 16); s[5] += asf(v.z & 0xffff0000u);
      s[6] += asf(v.w << 16); s[7] += asf(v.w & 0xffff0000u);
    }
    uint4 o = { cvt_pk(s[0], s[1]), cvt_pk(s[2], s[3]),
                cvt_pk(s[4], s[5]), cvt_pk(s[6], s[7]) };
    *(uint4*)&hsum_out[(blk * 8 + node) * 256 + chunk * 8] = o;
  }

  const int lane = tid & 63, wv = tid >> 6;   // wv = rowtile (16 rows)
  const int g = lane >> 4, r = lane & 15;
  const int row = wv * 16 + r;                // local nh row
  const int nodeL = row >> 3;                 // local node
  const float* ncb = nc + (size_t)blk * 16384 + row * 256;
  const ushort_t* Wr = WfT + r * 256;

#pragma unroll
  for (int cg = 0; cg < 4; ++cg) {
    f32x4 acc[4] = {};
#pragma unroll
    for (int kb = 0; kb < 8; ++kb) {
      int kc = kb * 32 + g * 8;
      bf16x8 bfrag = *(const bf16x8*)&As[swz(row, kc)];
#pragma unroll
      for (int ct = 0; ct < 4; ++ct) {
        bf16x8 afrag = *(const bf16x8*)&Wr[(cg * 64 + ct * 16) * 256 + kc];
        acc[ct] = __builtin_amdgcn_mfma_f32_16x16x32_bf16(afrag, bfrag, acc[ct], 0, 0, 0);
      }
    }
#pragma unroll
    for (int ct = 0; ct < 4; ++ct) {
      int col = cg * 64 + ct * 16 + g * 4;
      float4 ncv = *(const float4*)&ncb[col];
      float4 bv  = *(const float4*)&bias_s[col];
      uint2 fv   = *(const uint2*)&fin_s[nodeL * 256 + col];
      float f0 = sigmoidf_(acc[ct][0] + bv.x + asf(fv.x << 16));
      float f1 = sigmoidf_(acc[ct][1] + bv.y + asf(fv.x & 0xffff0000u));
      float f2 = sigmoidf_(acc[ct][2] + bv.z + asf(fv.y << 16));
      float f3 = sigmoidf_(acc[ct][3] + bv.w + asf(fv.y & 0xffff0000u));
      float p0 = f0 * ncv.x, p1 = f1 * ncv.y, p2 = f2 * ncv.z, p3 = f3 * ncv.w;
      p0 += __shfl_xor(p0, 1); p1 += __shfl_xor(p1, 1);
      p2 += __shfl_xor(p2, 1); p3 += __shfl_xor(p3, 1);
      p0 += __shfl_xor(p0, 2); p1 += __shfl_xor(p1, 2);
      p2 += __shfl_xor(p2, 2); p3 += __shfl_xor(p3, 2);
      p0 += __shfl_xor(p0, 4); p1 += __shfl_xor(p1, 4);
      p2 += __shfl_xor(p2, 4); p3 += __shfl_xor(p3, 4);
      if ((lane & 7) == 0) {
        uint2 o = { cvt_pk(p0, p1), cvt_pk(p2, p3) };
        *(uint2*)&cau_out[(blk * 8 + nodeL) * 512 + col] = o;
      }
    }
  }
}

// ---------------- k3: iou_aggr GEMM + node func ------------------------------
__global__ __launch_bounds__(256) void k_final(
    const ushort_t* __restrict__ hsum, const ushort_t* __restrict__ WaggrT,
    const float* __restrict__ b_iou, const float* __restrict__ b_aggr,
    const ushort_t* io_in, const ushort_t* cau_in,
    float* out_h, float* out_c) {
  __shared__ __align__(16) ushort_t As[16 * 256];
  __shared__ __align__(16) ushort_t Bs[64 * 256];
  __shared__ __align__(16) ushort_t Ios[16 * 512];
  __shared__ __align__(16) ushort_t CUs[16 * 512];
  __shared__ float bias_s[768];
  const int tid = threadIdx.x;
  const int blk = blockIdx.x;

  const ushort8_t* Ag = (const ushort8_t*)(hsum + blk * 4096);
#pragma unroll
  for (int it = 0; it < 2; ++it) {
    int idx8 = tid + it * 256;
    int row = idx8 >> 5, col = (idx8 & 31) << 3;
    *(ushort8_t*)&As[swz(row, col)] = Ag[idx8];
  }
  const ushort8_t* Ig = (const ushort8_t*)(io_in + blk * 8192);
  const ushort8_t* Cg = (const ushort8_t*)(cau_in + blk * 8192);
#pragma unroll
  for (int it = 0; it < 4; ++it) {
    int idx8 = tid + it * 256;
    ((ushort8_t*)Ios)[idx8] = Ig[idx8];
    ((ushort8_t*)CUs)[idx8] = Cg[idx8];
  }
#pragma unroll
  for (int it = 0; it < 3; ++it) {
    int c = tid + it * 256;
    bias_s[c] = b_iou[c] + b_aggr[c];
  }
  __syncthreads();

  const int lane = tid & 63, wv = tid >> 6;
  const int g = lane >> 4, r = lane & 15;
  f32x4 acc[12] = {};
#pragma unroll
  for (int t = 0; t < 12; ++t) {
    if (t) __syncthreads();
    const ushort8_t* Bg = (const ushort8_t*)(WaggrT + t * 64 * 256);
#pragma unroll
    for (int it = 0; it < 8; ++it) {
      int idx8 = tid + it * 256;
      int row = idx8 >> 5, col = (idx8 & 31) << 3;
      *(ushort8_t*)&Bs[swz(row, col)] = Bg[idx8];
    }
    __syncthreads();
#pragma unroll
    for (int kb = 0; kb < 8; ++kb) {
      int kc = kb * 32 + g * 8;
      bf16x8 a = *(const bf16x8*)&As[swz(r, kc)];
      bf16x8 b = *(const bf16x8*)&Bs[swz(wv * 16 + r, kc)];
      acc[t] = __builtin_amdgcn_mfma_f32_16x16x32_bf16(a, b, acc[t], 0, 0, 0);
    }
  }
#pragma unroll
  for (int t = 0; t < 4; ++t)
#pragma unroll
    for (int i = 0; i < 4; ++i) {
      int nl = g * 4 + i;
      int col = t * 64 + wv * 16 + r;
      float iv = acc[t][i]     + bias_s[col]       + bf2f(Ios[nl * 512 + col]);
      float ov = acc[t + 4][i] + bias_s[256 + col] + bf2f(Ios[nl * 512 + 256 + col]);
      float uv = acc[t + 8][i] + bias_s[512 + col] + bf2f(CUs[nl * 512 + 256 + col]);
      float ca = bf2f(CUs[nl * 512 + col]);
      float cn = sigmoidf_(iv) * tanhf_(uv) + ca;
      float hn = sigmoidf_(ov) * tanhf_(cn);
      int node = blk * 16 + nl;
      out_c[node * 256 + col] = cn;
      out_h[node * 256 + col] = hn;
    }
}

extern "C" void kernel_launch(void* const* d_in, const int* in_sizes, int n_in,
                              void* d_out, int out_size, void* d_ws, size_t ws_size,
                              hipStream_t stream) {
  const float* x      = (const float*)d_in[0];
  const float* nh     = (const float*)d_in[1];
  const float* nc     = (const float*)d_in[2];
  const float* W_iou  = (const float*)d_in[3];
  const float* b_iou  = (const float*)d_in[4];
  const float* W_fin  = (const float*)d_in[5];
  const float* b_fin  = (const float*)d_in[6];
  const float* W_f    = (const float*)d_in[7];
  const float* b_f    = (const float*)d_in[8];
  const float* W_aggr = (const float*)d_in[9];
  const float* b_aggr = (const float*)d_in[10];

  char* ws = (char*)d_ws;
  ushort_t* WcatT  = (ushort_t*)ws;                                  // 512 KB
  ushort_t* WfT    = (ushort_t*)(ws + (512 << 10));                  // 128 KB
  ushort_t* WaggrT = (ushort_t*)(ws + (640 << 10));                  // 384 KB
  ushort_t* f_in   = (ushort_t*)(ws + (1 << 20));                    // 16 MB
  ushort_t* hsum   = (ushort_t*)(ws + (1 << 20) + (16 << 20));       // 16 MB

  float* out_h = (float*)d_out;
  float* out_c = out_h + (size_t)NN * HH;
  ushort_t* io_v  = (ushort_t*)out_h;   // per node: [i 256 | o 256] bf16
  ushort_t* cau_v = (ushort_t*)out_c;   // per node: [c_aggr 256 | u 256] bf16

  k_prep<<<2048, 256, 0, stream>>>(W_iou, W_fin, W_f, W_aggr, WcatT, WfT, WaggrT);
  k_iou<<<2048, 256, 0, stream>>>(x, WcatT, b_iou, b_fin, io_v, cau_v, f_in);
  k_fgate<<<4096, 256, 0, stream>>>(nh, nc, WfT, b_f, f_in, cau_v, hsum);
  k_final<<<2048, 256, 0, stream>>>(hsum, WaggrT, b_iou, b_aggr, io_v, cau_v, out_h, out_c);
}

// Round 3
// 306.586 us; speedup vs baseline: 1.4601x; 1.4601x over previous
//
#include <hip/hip_runtime.h>
#include <hip/hip_bf16.h>
#include <stdint.h>

#define NN 32768
#define HH 256

typedef short bf16x8 __attribute__((ext_vector_type(8)));
typedef float f32x4 __attribute__((ext_vector_type(4)));
typedef unsigned short ushort_t;
typedef unsigned short ushort8_t __attribute__((ext_vector_type(8)));
typedef unsigned short ushort4_t __attribute__((ext_vector_type(4)));

__device__ __forceinline__ ushort_t f2bf(float f) {
  union { float f; unsigned u; } v; v.f = f;
  unsigned u = v.u;
  unsigned r = (u + 0x7FFFu + ((u >> 16) & 1u)) >> 16;  // RNE (cold paths)
  return (ushort_t)r;
}
__device__ __forceinline__ float bf2f(ushort_t h) {
  union { unsigned u; float f; } v; v.u = ((unsigned)h) << 16;
  return v.f;
}
__device__ __forceinline__ float asf(unsigned u) {
  union { unsigned u; float f; } v; v.u = u; return v.f;
}
// HW packed f32->bf16 (RNE), 1 instr per 2 elems
__device__ __forceinline__ unsigned cvt_pk(float lo, float hi) {
  unsigned r;
  asm("v_cvt_pk_bf16_f32 %0, %1, %2" : "=v"(r) : "v"(lo), "v"(hi));
  return r;
}
__device__ __forceinline__ float sigmoidf_(float x) {
  float e = __builtin_amdgcn_exp2f(-1.4426950408889634f * x);
  return __builtin_amdgcn_rcpf(1.f + e);
}
__device__ __forceinline__ float tanhf_(float x) {
  float ax = fminf(fabsf(x), 15.f);
  float e = __builtin_amdgcn_exp2f(2.8853900817779268f * ax);  // exp(2ax)
  float t = (e - 1.f) * __builtin_amdgcn_rcpf(e + 1.f);
  return copysignf(t, x);
}
// XOR swizzle: 16B chunks within a 256-elem (512B) row, spread across rows&7
__device__ __forceinline__ int swz(int row, int col) {
  return row * 256 + ((((col >> 3) ^ (row & 7)) << 3) | (col & 7));
}

// ---------------- prep: weights -> bf16, transposed to [N][K] ----------------
__global__ void k_prep(const float* __restrict__ W_iou, const float* __restrict__ W_fin,
                       const float* __restrict__ W_f, const float* __restrict__ W_aggr,
                       ushort_t* __restrict__ WcatT, ushort_t* __restrict__ WfT,
                       ushort_t* __restrict__ WaggrT) {
  int tid = blockIdx.x * 256 + threadIdx.x;
  if (tid < 262144) {                       // WcatT [1024][256]
    int n = tid >> 8, k = tid & 255;
    float v = (n < 768) ? W_iou[k * 768 + n] : W_fin[k * 256 + (n - 768)];
    WcatT[tid] = f2bf(v);
  } else if (tid < 327680) {                // WfT [256][256]
    int t2 = tid - 262144; int n = t2 >> 8, k = t2 & 255;
    WfT[t2] = f2bf(W_f[k * 256 + n]);
  } else if (tid < 524288) {                // WaggrT [768][256]
    int t3 = tid - 327680; int n = t3 >> 8, k = t3 & 255;
    WaggrT[t3] = f2bf(W_aggr[k * 768 + n]);
  }
}

// ---------------- k1: iouf = x @ [W_iou | W_fin] + bias ----------------------
__global__ __launch_bounds__(256) void k_iou(
    const float* __restrict__ x, const ushort_t* __restrict__ WcatT,
    const float* __restrict__ b_iou, const float* __restrict__ b_fin,
    ushort_t* __restrict__ io_out, ushort_t* __restrict__ cau_out,
    ushort_t* __restrict__ f_out) {
  __shared__ __align__(16) ushort_t As[64 * 256];
  __shared__ __align__(16) ushort_t Bs[64 * 256];
  __shared__ float bias_s[64];
  const int tid = threadIdx.x;
  const int mt = blockIdx.x >> 2;
  const int nt = blockIdx.x & 3;

  const float4* Ag = (const float4*)(x + (size_t)mt * 64 * 256);
#pragma unroll
  for (int it = 0; it < 16; ++it) {
    int idx4 = tid + it * 256;
    float4 v = Ag[idx4];
    int row = idx4 >> 6, col = (idx4 & 63) << 2;
    uint2 b = { cvt_pk(v.x, v.y), cvt_pk(v.z, v.w) };
    *(uint2*)&As[swz(row, col)] = b;
  }

  const int lane = tid & 63, wv = tid >> 6;
  const int g = lane >> 4, r = lane & 15;
  const int wm = wv >> 1, wn = wv & 1;

  for (int s = 0; s < 4; ++s) {
    __syncthreads();
    const int ct = nt * 4 + s;  // 64-col tile index in [0,16)
    const ushort8_t* Bg = (const ushort8_t*)(WcatT + (size_t)ct * 64 * 256);
#pragma unroll
    for (int it = 0; it < 8; ++it) {
      int idx8 = tid + it * 256;
      int row = idx8 >> 5, col = (idx8 & 31) << 3;
      *(ushort8_t*)&Bs[swz(row, col)] = Bg[idx8];
    }
    if (tid < 64) {
      int c = ct * 64 + tid;
      bias_s[tid] = (c < 768) ? b_iou[c] : b_fin[c - 768];
    }
    __syncthreads();

    f32x4 acc[2][2] = {};
#pragma unroll
    for (int kb = 0; kb < 8; ++kb) {
      int kc = kb * 32 + g * 8;
      bf16x8 a0 = *(const bf16x8*)&As[swz(wm * 32 + r, kc)];
      bf16x8 a1 = *(const bf16x8*)&As[swz(wm * 32 + 16 + r, kc)];
      bf16x8 b0 = *(const bf16x8*)&Bs[swz(wn * 32 + r, kc)];
      bf16x8 b1 = *(const bf16x8*)&Bs[swz(wn * 32 + 16 + r, kc)];
      acc[0][0] = __builtin_amdgcn_mfma_f32_16x16x32_bf16(a0, b0, acc[0][0], 0, 0, 0);
      acc[0][1] = __builtin_amdgcn_mfma_f32_16x16x32_bf16(a0, b1, acc[0][1], 0, 0, 0);
      acc[1][0] = __builtin_amdgcn_mfma_f32_16x16x32_bf16(a1, b0, acc[1][0], 0, 0, 0);
      acc[1][1] = __builtin_amdgcn_mfma_f32_16x16x32_bf16(a1, b1, acc[1][1], 0, 0, 0);
    }
#pragma unroll
    for (int mi = 0; mi < 2; ++mi)
#pragma unroll
      for (int ni = 0; ni < 2; ++ni)
#pragma unroll
        for (int i = 0; i < 4; ++i) {
          int node = mt * 64 + wm * 32 + mi * 16 + g * 4 + i;
          int colL = wn * 32 + ni * 16 + r;
          int col = ct * 64 + colL;
          ushort_t hv = f2bf(acc[mi][ni][i] + bias_s[colL]);
          if (col < 512)      io_out[node * 512 + col] = hv;
          else if (col < 768) cau_out[node * 512 + (col - 256)] = hv;
          else                f_out[node * 256 + (col - 768)] = hv;
        }
  }
}

// ---------------- k2: f-path streamer --------------------------------------
// W_f^T slice held in REGISTERS (64 VGPR/lane, zero reloads). Block = 4 waves;
// wave w owns cols half*128 + w*32. 16 iterations of 16 nh-rows each,
// double-buffered 8KB LDS tile. Blocks b and b+8 share rows (same XCD -> L2).
__global__ __launch_bounds__(256, 3) void k_fgate(
    const float* __restrict__ nh, const float* __restrict__ nc,
    const ushort_t* __restrict__ WfT, const float* __restrict__ b_f,
    const ushort_t* __restrict__ f_in,
    ushort_t* __restrict__ cau_out, ushort_t* __restrict__ hsum_out) {
  __shared__ __align__(16) ushort_t As[2][16 * 256];   // 8KB x2
  const int tid = threadIdx.x;
  const int b = blockIdx.x;
  const int half = (b >> 3) & 1;                 // col half (0/1)
  const int grp = ((b >> 4) << 3) | (b & 7);     // row group, pairs co-XCD
  const int lane = tid & 63, wv = tid >> 6;
  const int g = lane >> 4, r = lane & 15;
  const int mb = half * 128 + wv * 32;           // wave's col base

  // --- W_f^T fragments: 2 col-tiles x 8 k-blocks, resident in VGPRs ---
  bf16x8 wfrag[2][8];
#pragma unroll
  for (int ct = 0; ct < 2; ++ct)
#pragma unroll
    for (int kb = 0; kb < 8; ++kb)
      wfrag[ct][kb] = *(const bf16x8*)&WfT[(mb + ct * 16 + r) * 256 + kb * 32 + g * 8];

  float4 bias0 = *(const float4*)&b_f[mb + g * 4];
  float4 bias1 = *(const float4*)&b_f[mb + 16 + g * 4];

  const int srow = tid >> 4, spart = tid & 15;   // staging: row, 16-col part
  const float* sbase = nh + (size_t)grp * 16 * 16 * 256 + srow * 256 + spart * 16;

  // prologue: stage chunk 0 into buf 0
  {
    float4 v0 = *(const float4*)(sbase + 0);
    float4 v1 = *(const float4*)(sbase + 4);
    float4 v2 = *(const float4*)(sbase + 8);
    float4 v3 = *(const float4*)(sbase + 12);
    uint4 p0 = { cvt_pk(v0.x, v0.y), cvt_pk(v0.z, v0.w),
                 cvt_pk(v1.x, v1.y), cvt_pk(v1.z, v1.w) };
    uint4 p1 = { cvt_pk(v2.x, v2.y), cvt_pk(v2.z, v2.w),
                 cvt_pk(v3.x, v3.y), cvt_pk(v3.z, v3.w) };
    *(uint4*)&As[0][swz(srow, spart * 16)] = p0;
    *(uint4*)&As[0][swz(srow, spart * 16 + 8)] = p1;
  }
  __syncthreads();

  for (int it = 0; it < 16; ++it) {
    const int chunk = grp * 16 + it;
    const int rb = chunk * 16;
    const ushort_t* cur = As[it & 1];

    // issue next-chunk global loads early (hide HBM latency under MFMA)
    float4 v0, v1, v2, v3;
    if (it < 15) {
      const float* nb = sbase + (it + 1) * 16 * 256;
      v0 = *(const float4*)(nb + 0);
      v1 = *(const float4*)(nb + 4);
      v2 = *(const float4*)(nb + 8);
      v3 = *(const float4*)(nb + 12);
    }
    // nc / f_input for this iter (coalesced float4 / uint2)
    const float* ncr = nc + (size_t)(rb + r) * 256 + mb;
    float4 nc0 = *(const float4*)(ncr + g * 4);
    float4 nc1 = *(const float4*)(ncr + 16 + g * 4);
    const int node = chunk * 2 + (r >> 3);
    uint2 fv0 = *(const uint2*)&f_in[node * 256 + mb + g * 4];
    uint2 fv1 = *(const uint2*)&f_in[node * 256 + mb + 16 + g * 4];

    f32x4 acc0 = {}, acc1 = {};
#pragma unroll
    for (int kb = 0; kb < 8; ++kb) {
      bf16x8 bf = *(const bf16x8*)&cur[swz(r, kb * 32 + g * 8)];
      acc0 = __builtin_amdgcn_mfma_f32_16x16x32_bf16(wfrag[0][kb], bf, acc0, 0, 0, 0);
      acc1 = __builtin_amdgcn_mfma_f32_16x16x32_bf16(wfrag[1][kb], bf, acc1, 0, 0, 0);
    }

    // stage next chunk into the other buffer
    if (it < 15) {
      ushort_t* nxt = (ushort_t*)As[(it + 1) & 1];
      uint4 p0 = { cvt_pk(v0.x, v0.y), cvt_pk(v0.z, v0.w),
                   cvt_pk(v1.x, v1.y), cvt_pk(v1.z, v1.w) };
      uint4 p1 = { cvt_pk(v2.x, v2.y), cvt_pk(v2.z, v2.w),
                   cvt_pk(v3.x, v3.y), cvt_pk(v3.z, v3.w) };
      *(uint4*)&nxt[swz(srow, spart * 16)] = p0;
      *(uint4*)&nxt[swz(srow, spart * 16 + 8)] = p1;
    }

    // hsum for this block's col-half (reads current buf)
    {
      const int hn = tid >> 7;
      const int kc = half * 128 + (tid & 127);
      float s = 0.f;
#pragma unroll
      for (int c = 0; c < 8; ++c) s += bf2f(cur[swz(hn * 8 + c, kc)]);
      hsum_out[(chunk * 2 + hn) * 256 + kc] = f2bf(s);
    }

    // gates + f*nc + child reduction
    float f0 = sigmoidf_(acc0[0] + bias0.x + asf(fv0.x << 16));
    float f1 = sigmoidf_(acc0[1] + bias0.y + asf(fv0.x & 0xffff0000u));
    float f2 = sigmoidf_(acc0[2] + bias0.z + asf(fv0.y << 16));
    float f3 = sigmoidf_(acc0[3] + bias0.w + asf(fv0.y & 0xffff0000u));
    float f4 = sigmoidf_(acc1[0] + bias1.x + asf(fv1.x << 16));
    float f5 = sigmoidf_(acc1[1] + bias1.y + asf(fv1.x & 0xffff0000u));
    float f6 = sigmoidf_(acc1[2] + bias1.z + asf(fv1.y << 16));
    float f7 = sigmoidf_(acc1[3] + bias1.w + asf(fv1.y & 0xffff0000u));
    float p0 = f0 * nc0.x, p1 = f1 * nc0.y, p2 = f2 * nc0.z, p3 = f3 * nc0.w;
    float p4 = f4 * nc1.x, p5 = f5 * nc1.y, p6 = f6 * nc1.z, p7 = f7 * nc1.w;
    p0 += __shfl_xor(p0, 1); p1 += __shfl_xor(p1, 1); p2 += __shfl_xor(p2, 1); p3 += __shfl_xor(p3, 1);
    p4 += __shfl_xor(p4, 1); p5 += __shfl_xor(p5, 1); p6 += __shfl_xor(p6, 1); p7 += __shfl_xor(p7, 1);
    p0 += __shfl_xor(p0, 2); p1 += __shfl_xor(p1, 2); p2 += __shfl_xor(p2, 2); p3 += __shfl_xor(p3, 2);
    p4 += __shfl_xor(p4, 2); p5 += __shfl_xor(p5, 2); p6 += __shfl_xor(p6, 2); p7 += __shfl_xor(p7, 2);
    p0 += __shfl_xor(p0, 4); p1 += __shfl_xor(p1, 4); p2 += __shfl_xor(p2, 4); p3 += __shfl_xor(p3, 4);
    p4 += __shfl_xor(p4, 4); p5 += __shfl_xor(p5, 4); p6 += __shfl_xor(p6, 4); p7 += __shfl_xor(p7, 4);
    if ((lane & 7) == 0) {
      uint2 o0 = { cvt_pk(p0, p1), cvt_pk(p2, p3) };
      uint2 o1 = { cvt_pk(p4, p5), cvt_pk(p6, p7) };
      ushort_t* co = cau_out + (size_t)node * 512;
      *(uint2*)&co[mb + g * 4] = o0;
      *(uint2*)&co[mb + 16 + g * 4] = o1;
    }
    __syncthreads();
  }
}

// ---------------- k3: iou_aggr GEMM + node func ------------------------------
__global__ __launch_bounds__(256) void k_final(
    const ushort_t* __restrict__ hsum, const ushort_t* __restrict__ WaggrT,
    const float* __restrict__ b_iou, const float* __restrict__ b_aggr,
    const ushort_t* io_in, const ushort_t* cau_in,
    float* out_h, float* out_c) {
  __shared__ __align__(16) ushort_t As[16 * 256];
  __shared__ __align__(16) ushort_t Bs[64 * 256];
  __shared__ __align__(16) ushort_t Ios[16 * 512];
  __shared__ __align__(16) ushort_t CUs[16 * 512];
  __shared__ float bias_s[768];
  const int tid = threadIdx.x;
  const int blk = blockIdx.x;

  const ushort8_t* Ag = (const ushort8_t*)(hsum + blk * 4096);
#pragma unroll
  for (int it = 0; it < 2; ++it) {
    int idx8 = tid + it * 256;
    int row = idx8 >> 5, col = (idx8 & 31) << 3;
    *(ushort8_t*)&As[swz(row, col)] = Ag[idx8];
  }
  const ushort8_t* Ig = (const ushort8_t*)(io_in + blk * 8192);
  const ushort8_t* Cg = (const ushort8_t*)(cau_in + blk * 8192);
#pragma unroll
  for (int it = 0; it < 4; ++it) {
    int idx8 = tid + it * 256;
    ((ushort8_t*)Ios)[idx8] = Ig[idx8];
    ((ushort8_t*)CUs)[idx8] = Cg[idx8];
  }
#pragma unroll
  for (int it = 0; it < 3; ++it) {
    int c = tid + it * 256;
    bias_s[c] = b_iou[c] + b_aggr[c];
  }
  __syncthreads();

  const int lane = tid & 63, wv = tid >> 6;
  const int g = lane >> 4, r = lane & 15;
  f32x4 acc[12] = {};
#pragma unroll
  for (int t = 0; t < 12; ++t) {
    if (t) __syncthreads();
    const ushort8_t* Bg = (const ushort8_t*)(WaggrT + t * 64 * 256);
#pragma unroll
    for (int it = 0; it < 8; ++it) {
      int idx8 = tid + it * 256;
      int row = idx8 >> 5, col = (idx8 & 31) << 3;
      *(ushort8_t*)&Bs[swz(row, col)] = Bg[idx8];
    }
    __syncthreads();
#pragma unroll
    for (int kb = 0; kb < 8; ++kb) {
      int kc = kb * 32 + g * 8;
      bf16x8 a = *(const bf16x8*)&As[swz(r, kc)];
      bf16x8 b = *(const bf16x8*)&Bs[swz(wv * 16 + r, kc)];
      acc[t] = __builtin_amdgcn_mfma_f32_16x16x32_bf16(a, b, acc[t], 0, 0, 0);
    }
  }
#pragma unroll
  for (int t = 0; t < 4; ++t)
#pragma unroll
    for (int i = 0; i < 4; ++i) {
      int nl = g * 4 + i;
      int col = t * 64 + wv * 16 + r;
      float iv = acc[t][i]     + bias_s[col]       + bf2f(Ios[nl * 512 + col]);
      float ov = acc[t + 4][i] + bias_s[256 + col] + bf2f(Ios[nl * 512 + 256 + col]);
      float uv = acc[t + 8][i] + bias_s[512 + col] + bf2f(CUs[nl * 512 + 256 + col]);
      float ca = bf2f(CUs[nl * 512 + col]);
      float cn = sigmoidf_(iv) * tanhf_(uv) + ca;
      float hn = sigmoidf_(ov) * tanhf_(cn);
      int node = blk * 16 + nl;
      out_c[node * 256 + col] = cn;
      out_h[node * 256 + col] = hn;
    }
}

extern "C" void kernel_launch(void* const* d_in, const int* in_sizes, int n_in,
                              void* d_out, int out_size, void* d_ws, size_t ws_size,
                              hipStream_t stream) {
  const float* x      = (const float*)d_in[0];
  const float* nh     = (const float*)d_in[1];
  const float* nc     = (const float*)d_in[2];
  const float* W_iou  = (const float*)d_in[3];
  const float* b_iou  = (const float*)d_in[4];
  const float* W_fin  = (const float*)d_in[5];
  const float* b_fin  = (const float*)d_in[6];
  const float* W_f    = (const float*)d_in[7];
  const float* b_f    = (const float*)d_in[8];
  const float* W_aggr = (const float*)d_in[9];
  const float* b_aggr = (const float*)d_in[10];

  char* ws = (char*)d_ws;
  ushort_t* WcatT  = (ushort_t*)ws;                                  // 512 KB
  ushort_t* WfT    = (ushort_t*)(ws + (512 << 10));                  // 128 KB
  ushort_t* WaggrT = (ushort_t*)(ws + (640 << 10));                  // 384 KB
  ushort_t* f_in   = (ushort_t*)(ws + (1 << 20));                    // 16 MB
  ushort_t* hsum   = (ushort_t*)(ws + (1 << 20) + (16 << 20));       // 16 MB

  float* out_h = (float*)d_out;
  float* out_c = out_h + (size_t)NN * HH;
  ushort_t* io_v  = (ushort_t*)out_h;   // per node: [i 256 | o 256] bf16
  ushort_t* cau_v = (ushort_t*)out_c;   // per node: [c_aggr 256 | u 256] bf16

  k_prep<<<2048, 256, 0, stream>>>(W_iou, W_fin, W_f, W_aggr, WcatT, WfT, WaggrT);
  k_iou<<<2048, 256, 0, stream>>>(x, WcatT, b_iou, b_fin, io_v, cau_v, f_in);
  k_fgate<<<2048, 256, 0, stream>>>(nh, nc, WfT, b_f, f_in, cau_v, hsum);
  k_final<<<2048, 256, 0, stream>>>(hsum, WaggrT, b_iou, b_aggr, io_v, cau_v, out_h, out_c);
}